// Round 5
// baseline (259.780 us; speedup 1.0000x reference)
//
#include <hip/hip_runtime.h>

// ---------------- helpers ----------------

typedef __bf16 bf16x8 __attribute__((ext_vector_type(8)));
typedef float  f32x4  __attribute__((ext_vector_type(4)));

__device__ __forceinline__ unsigned short f2bf(float x) {
    unsigned int u = __builtin_bit_cast(unsigned int, x);
    u = (u + 0x7fffu + ((u >> 16) & 1u)) >> 16;
    return (unsigned short)u;
}

__device__ __forceinline__ void gl2lds16(const unsigned short* g, unsigned short* l) {
    __builtin_amdgcn_global_load_lds(
        (const __attribute__((address_space(1))) unsigned int*)g,
        (__attribute__((address_space(3))) unsigned int*)l,
        16, 0, 0);
}

__device__ __forceinline__ float sigf(float x) {
    return __builtin_amdgcn_rcpf(1.f + __expf(-x));
}
__device__ __forceinline__ float tanh_fast(float x) {
    return 2.f * __builtin_amdgcn_rcpf(1.f + __expf(-2.f * x)) - 1.f;
}

// ---------------- fused conversion kernel ----------------
// blocks [0,16384): activations -> bf16 A [4096][4096]
// blocks [16384,32768): weights -> bf16 B^T with gate-interleave permutation
//   Bt[p][k] = Wcat[k][ g*1024 + u ],  p = (u>>6)*256 + ((u>>4)&3)*64 + g*16 + (u&15)

__global__ void convert_AB(const float* __restrict__ A0, const float* __restrict__ A1,
                           const float* __restrict__ A2, const float* __restrict__ A3,
                           const float* __restrict__ Wb, const float* __restrict__ W1,
                           const float* __restrict__ W2, const float* __restrict__ Wl,
                           unsigned short* __restrict__ Abf,
                           unsigned short* __restrict__ Bt) {
    __shared__ float t[32][33];
    if (blockIdx.x < 16384) {
        int idx = blockIdx.x * 256 + threadIdx.x;
        int e0  = idx * 4;
        int b   = e0 >> 12;
        int k   = e0 & 4095;
        const float* S = (k < 1024) ? A0 : (k < 2048) ? A1 : (k < 3072) ? A2 : A3;
        int col = k & 1023;
        const float4 v = *reinterpret_cast<const float4*>(S + (size_t)b * 1024 + col);
        ushort4 o;
        o.x = f2bf(v.x); o.y = f2bf(v.y); o.z = f2bf(v.z); o.w = f2bf(v.w);
        *reinterpret_cast<ushort4*>(Abf + (size_t)b * 4096 + k) = o;
    } else {
        int tile = blockIdx.x - 16384;    // 128 j-tiles x 128 k-tiles
        int jt = tile & 127, kt = tile >> 7;
        int j0 = jt * 32, k0 = kt * 32;
        int ksel = k0 >> 10;
        const float* S = (ksel == 0) ? Wb : (ksel == 1) ? W1 : (ksel == 2) ? W2 : Wl;
        int kloc = k0 & 1023;
        int tx = threadIdx.x & 31, ty = threadIdx.x >> 5;
#pragma unroll
        for (int i = 0; i < 4; ++i) {
            int r = ty + i * 8;
            t[r][tx] = S[(size_t)(kloc + r) * 4096 + j0 + tx];
        }
        __syncthreads();
        int g = j0 >> 10;
        int nbase = j0 & 1023;
#pragma unroll
        for (int i = 0; i < 4; ++i) {
            int jj = ty + i * 8;
            int u  = nbase + jj;
            int p  = (u >> 6) * 256 + ((u >> 4) & 3) * 64 + g * 16 + (u & 15);
            Bt[(size_t)p * 4096 + k0 + tx] = f2bf(t[tx][jj]);
        }
    }
}

// ---------------- 256x256 8-phase GEMM + fused LSTM epilogue ----------------
// Software-pipelined fragment reads: frags for phase P are ds_read during
// phase P-1's MFMA window; next-tile's 16 frags are read in ph3 AFTER the
// per-tile vmcnt fence + barrier (so staging has landed), hidden under
// MFMA16(3). No explicit lgkmcnt drain — compiler emits counted waits.

__global__ __launch_bounds__(512, 2) void gemm_lstm(
        const unsigned short* __restrict__ A,
        const unsigned short* __restrict__ Bt,
        const float* __restrict__ bias,
        const float* __restrict__ cprev,
        float* __restrict__ out) {
    __shared__ unsigned short lds[65536];          // 128 KiB
#define ASB(b) (lds + (b) * 16384)
#define BSB(b) (lds + 32768 + (b) * 16384)

    const int tid  = threadIdx.x;
    const int wid  = tid >> 6;
    const int lane = tid & 63;
    const int wm = wid >> 2, wn = wid & 3;         // 2 x 4 wave grid
    const int lr = lane & 15, lq = lane >> 4;
    const int bm = blockIdx.y, bc = blockIdx.x;

    // staging geometry: half-tile = 128 rows x 64 cols = 16 KB; 2 chunks/thread
    const int X0 = wid * 1024 + lane * 16;                 // j=0 portion, rows 0..63
    const int rs = X0 >> 7;
    const int cs = ((X0 & 127) ^ ((rs & 7) << 4)) >> 1;    // element col (pre-swizzled src)
    const unsigned short* Agb = A  + ((size_t)(bm * 256 + rs)) * 4096 + cs;
    const unsigned short* Bgb = Bt + ((size_t)(bc * 256 + rs)) * 4096 + cs;

    // ds_read fragment col offsets (elements), read-side swizzle
    const int swz = (lr & 7) << 4;
    const int ca0 = ((lq * 16) ^ swz) >> 1;        // ks=0
    const int ca1 = ((64 + lq * 16) ^ swz) >> 1;   // ks=1

    f32x4 acc[8][4] = {};                          // acc[mi][gate]
    bf16x8 afA[2][2], afB[2][2], afC[2][2], afD[2][2];
    bf16x8 bfr0[4][2], bfr1[4][2];

#define STAGE_A(b, h, kt) do {                                               \
        unsigned short* _d = ASB(b) + (h) * 8192 + wid * 512;                \
        const unsigned short* _s = Agb + (size_t)((h) * 128) * 4096 + (kt) * 64; \
        gl2lds16(_s, _d);                                                    \
        gl2lds16(_s + 64 * 4096, _d + 4096);                                 \
    } while (0)
#define STAGE_B(b, h, kt) do {                                               \
        unsigned short* _d = BSB(b) + (h) * 8192 + wid * 512;                \
        const unsigned short* _s = Bgb + (size_t)((h) * 128) * 4096 + (kt) * 64; \
        gl2lds16(_s, _d);                                                    \
        gl2lds16(_s + 64 * 4096, _d + 4096);                                 \
    } while (0)
#define LDA(buf, mi, cax) (*reinterpret_cast<const bf16x8*>((buf) + (wm * 128 + (mi) * 16 + lr) * 64 + (cax)))
#define LDB(buf, ni, cax) (*reinterpret_cast<const bf16x8*>((buf) + (wn * 64  + (ni) * 16 + lr) * 64 + (cax)))
#define RD_A(DST, BUF, MI0) do {                                             \
        _Pragma("unroll")                                                    \
        for (int m = 0; m < 2; ++m) {                                        \
            DST[m][0] = LDA(BUF, (MI0) + m, ca0);                            \
            DST[m][1] = LDA(BUF, (MI0) + m, ca1);                            \
        } } while (0)
#define RD_B(DST, BUF) do {                                                  \
        _Pragma("unroll")                                                    \
        for (int n = 0; n < 4; ++n) {                                        \
            DST[n][0] = LDB(BUF, n, ca0);                                    \
            DST[n][1] = LDB(BUF, n, ca1);                                    \
        } } while (0)
#define SBAR() __builtin_amdgcn_s_barrier()
#define VMFENCE() asm volatile("s_waitcnt vmcnt(4)" ::: "memory")
#define MFMA16(P, AF, BF)                                                    \
        __builtin_amdgcn_s_setprio(1);                                       \
        _Pragma("unroll")                                                    \
        for (int m = 0; m < 2; ++m)                                          \
        _Pragma("unroll")                                                    \
        for (int ks = 0; ks < 2; ++ks)                                       \
        _Pragma("unroll")                                                    \
        for (int ni = 0; ni < 4; ++ni)                                       \
            acc[(P)*2 + m][ni] = __builtin_amdgcn_mfma_f32_16x16x32_bf16(    \
                AF[m][ks], BF[ni][ks], acc[(P)*2 + m][ni], 0, 0, 0);         \
        __builtin_amdgcn_s_setprio(0)

    // One K-tile = 4 phases. PAR = t&1 (compile-time). BFC = current B-frags,
    // BFN = next-tile B-frags (loaded in ph3 after fence+barrier).
#define KITER(T, PAR, BFC, BFN) do {                                         \
        const unsigned short* Ac = ASB(PAR);                                 \
        const int ktA = ((T) < 63) ? (T) + 1 : 63;                           \
        const int ktB = ((T) < 62) ? (T) + 2 : 63;                           \
        /* ph0: afA,BFC preloaded; read afC (ph2); stage A-half0(t+1) */     \
        RD_A(afC, Ac, 4);                                                    \
        STAGE_A(PAR ^ 1, 0, ktA);                                            \
        SBAR();                                                              \
        MFMA16(0, afA, BFC);                                                 \
        SBAR();                                                              \
        /* ph1: read afD (ph3); stage A-half1(t+1) */                        \
        RD_A(afD, Ac, 6);                                                    \
        STAGE_A(PAR ^ 1, 1, ktA);                                            \
        SBAR();                                                              \
        MFMA16(1, afB, BFC);                                                 \
        SBAR();                                                              \
        /* ph2: stage B-half0(t+2) */                                        \
        STAGE_B(PAR, 0, ktB);                                                \
        SBAR();                                                              \
        MFMA16(2, afC, BFC);                                                 \
        SBAR();                                                              \
        /* ph3: stage B-half1(t+2); fence -> tile t+1 landed; read its frags */ \
        STAGE_B(PAR, 1, ktB);                                                \
        VMFENCE();                                                           \
        SBAR();                                                              \
        __builtin_amdgcn_sched_barrier(0);                                   \
        {                                                                    \
            const unsigned short* An = ASB(PAR ^ 1);                         \
            const unsigned short* Bn = BSB(PAR ^ 1);                         \
            RD_B(BFN, Bn);                                                   \
            RD_A(afA, An, 0);                                                \
            RD_A(afB, An, 2);                                                \
        }                                                                    \
        MFMA16(3, afD, BFC);                                                 \
        SBAR();                                                              \
    } while (0)

    // ---- prologue: tile0 A+B, tile1 B staged; fence; preload tile0 frags ----
    STAGE_A(0, 0, 0); STAGE_A(0, 1, 0);
    STAGE_B(0, 0, 0); STAGE_B(0, 1, 0);
    STAGE_B(1, 0, 1); STAGE_B(1, 1, 1);
    VMFENCE();                                     // tile0's 8 loads landed
    SBAR();
    __builtin_amdgcn_sched_barrier(0);
    RD_B(bfr0, BSB(0));
    RD_A(afA, ASB(0), 0);
    RD_A(afB, ASB(0), 2);

    for (int u = 0; u < 32; ++u) {
        const int t0 = 2 * u, t1 = 2 * u + 1;
        KITER(t0, 0, bfr0, bfr1);
        KITER(t1, 1, bfr1, bfr0);
    }

    // ---- fused LSTM epilogue: lane lr holds a,i,f,o of unit u in ni=0..3 ----
    const int un = bc * 64 + wn * 16 + lr;
    const float ba  = bias[un];
    const float bi  = bias[1024 + un];
    const float bfv = bias[2048 + un];
    const float bo  = bias[3072 + un];
    float* outh = out;
    float* outc = out + (size_t)4096 * 1024;

#pragma unroll
    for (int mi = 0; mi < 8; ++mi) {
        const int r0 = bm * 256 + wm * 128 + mi * 16 + lq * 4;
#pragma unroll
        for (int r = 0; r < 4; ++r) {
            const size_t off = (size_t)(r0 + r) * 1024 + un;
            const float a  = acc[mi][0][r] + ba;
            const float ii = acc[mi][1][r] + bi;
            const float ff = acc[mi][2][r] + bfv;
            const float oo = acc[mi][3][r] + bo;
            const float c  = tanh_fast(a) * sigf(ii) + sigf(ff) * cprev[off];
            outh[off] = sigf(oo) * tanh_fast(c);
            outc[off] = c;
        }
    }
#undef STAGE_A
#undef STAGE_B
#undef LDA
#undef LDB
#undef RD_A
#undef RD_B
#undef SBAR
#undef VMFENCE
#undef MFMA16
#undef KITER
#undef ASB
#undef BSB
}

// ---------------- launch ----------------

extern "C" void kernel_launch(void* const* d_in, const int* in_sizes, int n_in,
                              void* d_out, int out_size, void* d_ws, size_t ws_size,
                              hipStream_t stream) {
    const float* top_buf = (const float*)d_in[0];
    const float* s1      = (const float*)d_in[1];
    const float* s2      = (const float*)d_in[2];
    const float* hprev   = (const float*)d_in[3];
    const float* cprev   = (const float*)d_in[4];
    const float* Wb      = (const float*)d_in[5];
    const float* W1      = (const float*)d_in[6];
    const float* W2      = (const float*)d_in[7];
    const float* Wl      = (const float*)d_in[8];
    const float* bl      = (const float*)d_in[9];

    unsigned short* Abf = (unsigned short*)d_ws;                 // 32 MB
    unsigned short* Bt  = Abf + (size_t)4096 * 4096;             // 32 MB

    convert_AB<<<32768, 256, 0, stream>>>(top_buf, s1, s2, hprev,
                                          Wb, W1, W2, Wl, Abf, Bt);

    dim3 grid(16, 16);
    gemm_lstm<<<grid, 512, 0, stream>>>(Abf, Bt, bl, cprev, (float*)d_out);
}

// Round 6
// 147.704 us; speedup vs baseline: 1.7588x; 1.7588x over previous
//
#include <hip/hip_runtime.h>

// ---------------- helpers ----------------

typedef __bf16 bf16x8 __attribute__((ext_vector_type(8)));
typedef float  f32x4  __attribute__((ext_vector_type(4)));

__device__ __forceinline__ unsigned short f2bf(float x) {
    unsigned int u = __builtin_bit_cast(unsigned int, x);
    u = (u + 0x7fffu + ((u >> 16) & 1u)) >> 16;
    return (unsigned short)u;
}

__device__ __forceinline__ void gl2lds16(const unsigned short* g, unsigned short* l) {
    __builtin_amdgcn_global_load_lds(
        (const __attribute__((address_space(1))) unsigned int*)g,
        (__attribute__((address_space(3))) unsigned int*)l,
        16, 0, 0);
}

__device__ __forceinline__ float sigf(float x) {
    return __builtin_amdgcn_rcpf(1.f + __expf(-x));
}
__device__ __forceinline__ float tanh_fast(float x) {
    return 2.f * __builtin_amdgcn_rcpf(1.f + __expf(-2.f * x)) - 1.f;
}

// ---------------- fused conversion kernel ----------------
// blocks [0,16384): activations -> bf16 A [4096][4096]
// blocks [16384,32768): weights -> bf16 B^T with gate-interleave permutation
//   Bt[p][k] = Wcat[k][ g*1024 + u ],  p = (u>>6)*256 + ((u>>4)&3)*64 + g*16 + (u&15)

__global__ void convert_AB(const float* __restrict__ A0, const float* __restrict__ A1,
                           const float* __restrict__ A2, const float* __restrict__ A3,
                           const float* __restrict__ Wb, const float* __restrict__ W1,
                           const float* __restrict__ W2, const float* __restrict__ Wl,
                           unsigned short* __restrict__ Abf,
                           unsigned short* __restrict__ Bt) {
    __shared__ float t[32][33];
    if (blockIdx.x < 16384) {
        int idx = blockIdx.x * 256 + threadIdx.x;
        int e0  = idx * 4;
        int b   = e0 >> 12;
        int k   = e0 & 4095;
        const float* S = (k < 1024) ? A0 : (k < 2048) ? A1 : (k < 3072) ? A2 : A3;
        int col = k & 1023;
        const float4 v = *reinterpret_cast<const float4*>(S + (size_t)b * 1024 + col);
        ushort4 o;
        o.x = f2bf(v.x); o.y = f2bf(v.y); o.z = f2bf(v.z); o.w = f2bf(v.w);
        *reinterpret_cast<ushort4*>(Abf + (size_t)b * 4096 + k) = o;
    } else {
        int tile = blockIdx.x - 16384;    // 128 j-tiles x 128 k-tiles
        int jt = tile & 127, kt = tile >> 7;
        int j0 = jt * 32, k0 = kt * 32;
        int ksel = k0 >> 10;
        const float* S = (ksel == 0) ? Wb : (ksel == 1) ? W1 : (ksel == 2) ? W2 : Wl;
        int kloc = k0 & 1023;
        int tx = threadIdx.x & 31, ty = threadIdx.x >> 5;
#pragma unroll
        for (int i = 0; i < 4; ++i) {
            int r = ty + i * 8;
            t[r][tx] = S[(size_t)(kloc + r) * 4096 + j0 + tx];
        }
        __syncthreads();
        int g = j0 >> 10;
        int nbase = j0 & 1023;
#pragma unroll
        for (int i = 0; i < 4; ++i) {
            int jj = ty + i * 8;
            int u  = nbase + jj;
            int p  = (u >> 6) * 256 + ((u >> 4) & 3) * 64 + g * 16 + (u & 15);
            Bt[(size_t)p * 4096 + k0 + tx] = f2bf(t[tx][jj]);
        }
    }
}

// ---------------- 256x256 GEMM, 2-barrier K-tile + fused LSTM epilogue ----------------
// Barrier audit: only 2 syncs per K-tile are required.
//  B2 (after MFMA16(0)): all waves' B-frags are in registers -> B-buffer regions
//      of the current parity become writable for the t+2 B-stages.
//  B1 (tile end, after counted vmcnt(4)): tile t+1's A and B staging landed.
//  A-stages write the opposite-parity buffer -> safe any time after tile start.
// No per-phase barriers / lgkmcnt(0): the whole K-tile is one scheduling region,
// so compiler-counted lgkm waits let next-phase ds_reads run under current MFMA.

__global__ __launch_bounds__(512, 2) void gemm_lstm(
        const unsigned short* __restrict__ A,
        const unsigned short* __restrict__ Bt,
        const float* __restrict__ bias,
        const float* __restrict__ cprev,
        float* __restrict__ out) {
    __shared__ unsigned short lds[65536];          // 128 KiB
#define ASB(b) (lds + (b) * 16384)
#define BSB(b) (lds + 32768 + (b) * 16384)

    const int tid  = threadIdx.x;
    const int wid  = tid >> 6;
    const int lane = tid & 63;
    const int wm = wid >> 2, wn = wid & 3;         // 2 x 4 wave grid
    const int lr = lane & 15, lq = lane >> 4;
    const int bm = blockIdx.y, bc = blockIdx.x;

    // staging geometry: half-tile = 128 rows x 64 cols = 16 KB; 2 chunks/thread
    const int X0 = wid * 1024 + lane * 16;                 // j=0 portion, rows 0..63
    const int rs = X0 >> 7;
    const int cs = ((X0 & 127) ^ ((rs & 7) << 4)) >> 1;    // element col (pre-swizzled src)
    const unsigned short* Agb = A  + ((size_t)(bm * 256 + rs)) * 4096 + cs;
    const unsigned short* Bgb = Bt + ((size_t)(bc * 256 + rs)) * 4096 + cs;

    // ds_read fragment col offsets (elements), read-side swizzle
    const int swz = (lr & 7) << 4;
    const int ca0 = ((lq * 16) ^ swz) >> 1;        // ks=0
    const int ca1 = ((64 + lq * 16) ^ swz) >> 1;   // ks=1

    f32x4 acc[8][4] = {};                          // acc[mi][gate]

#define STAGE_A(b, h, kt) do {                                               \
        unsigned short* _d = ASB(b) + (h) * 8192 + wid * 512;                \
        const unsigned short* _s = Agb + (size_t)((h) * 128) * 4096 + (kt) * 64; \
        gl2lds16(_s, _d);                                                    \
        gl2lds16(_s + 64 * 4096, _d + 4096);                                 \
    } while (0)
#define STAGE_B(b, h, kt) do {                                               \
        unsigned short* _d = BSB(b) + (h) * 8192 + wid * 512;                \
        const unsigned short* _s = Bgb + (size_t)((h) * 128) * 4096 + (kt) * 64; \
        gl2lds16(_s, _d);                                                    \
        gl2lds16(_s + 64 * 4096, _d + 4096);                                 \
    } while (0)
#define LDA(buf, mi, cax) (*reinterpret_cast<const bf16x8*>((buf) + (wm * 128 + (mi) * 16 + lr) * 64 + (cax)))
#define LDB(buf, ni, cax) (*reinterpret_cast<const bf16x8*>((buf) + (wn * 64  + (ni) * 16 + lr) * 64 + (cax)))
#define RD_A(DST, BUF, MI0) do {                                             \
        _Pragma("unroll")                                                    \
        for (int m = 0; m < 2; ++m) {                                        \
            DST[m][0] = LDA(BUF, (MI0) + m, ca0);                            \
            DST[m][1] = LDA(BUF, (MI0) + m, ca1);                            \
        } } while (0)
#define RD_B(DST, BUF) do {                                                  \
        _Pragma("unroll")                                                    \
        for (int n = 0; n < 4; ++n) {                                        \
            DST[n][0] = LDB(BUF, n, ca0);                                    \
            DST[n][1] = LDB(BUF, n, ca1);                                    \
        } } while (0)
#define SBAR() __builtin_amdgcn_s_barrier()
#define VMFENCE() asm volatile("s_waitcnt vmcnt(4)" ::: "memory")
#define MFMA16(P, AF, BF)                                                    \
        __builtin_amdgcn_s_setprio(1);                                       \
        _Pragma("unroll")                                                    \
        for (int m = 0; m < 2; ++m)                                          \
        _Pragma("unroll")                                                    \
        for (int ks = 0; ks < 2; ++ks)                                       \
        _Pragma("unroll")                                                    \
        for (int ni = 0; ni < 4; ++ni)                                       \
            acc[(P)*2 + m][ni] = __builtin_amdgcn_mfma_f32_16x16x32_bf16(    \
                AF[m][ks], BF[ni][ks], acc[(P)*2 + m][ni], 0, 0, 0);         \
        __builtin_amdgcn_s_setprio(0)

#define KITER(T, PAR) do {                                                   \
        const unsigned short* Ac = ASB(PAR);                                 \
        const unsigned short* Bc = BSB(PAR);                                 \
        const int ktA = ((T) < 63) ? (T) + 1 : 63;                           \
        const int ktB = ((T) < 62) ? (T) + 2 : 63;                           \
        STAGE_A(PAR ^ 1, 0, ktA);                                            \
        STAGE_A(PAR ^ 1, 1, ktA);                                            \
        bf16x8 bfr[4][2];                                                    \
        bf16x8 af[2][2];                                                     \
        RD_B(bfr, Bc);                                                       \
        RD_A(af, Ac, 0);                                                     \
        MFMA16(0, af, bfr);                                                  \
        SBAR();   /* B2: all waves' B-frags in regs -> B region writable */  \
        STAGE_B(PAR, 0, ktB);                                                \
        STAGE_B(PAR, 1, ktB);                                                \
        RD_A(af, Ac, 2);                                                     \
        MFMA16(1, af, bfr);                                                  \
        RD_A(af, Ac, 4);                                                     \
        MFMA16(2, af, bfr);                                                  \
        RD_A(af, Ac, 6);                                                     \
        MFMA16(3, af, bfr);                                                  \
        VMFENCE();                                                           \
        SBAR();   /* B1: tile T+1 staged data ready */                       \
    } while (0)

    // ---- prologue: tile0 A+B, tile1 B staged ----
    STAGE_A(0, 0, 0); STAGE_A(0, 1, 0);
    STAGE_B(0, 0, 0); STAGE_B(0, 1, 0);
    STAGE_B(1, 0, 1); STAGE_B(1, 1, 1);
    VMFENCE();                                     // tile0's 8 loads landed
    SBAR();

    for (int u = 0; u < 32; ++u) {
        KITER(2 * u, 0);
        KITER(2 * u + 1, 1);
    }

    // ---- fused LSTM epilogue: lane lr holds a,i,f,o of unit u in ni=0..3 ----
    const int un = bc * 64 + wn * 16 + lr;
    const float ba  = bias[un];
    const float bi  = bias[1024 + un];
    const float bfv = bias[2048 + un];
    const float bo  = bias[3072 + un];
    float* outh = out;
    float* outc = out + (size_t)4096 * 1024;

#pragma unroll
    for (int mi = 0; mi < 8; ++mi) {
        const int r0 = bm * 256 + wm * 128 + mi * 16 + lq * 4;
#pragma unroll
        for (int r = 0; r < 4; ++r) {
            const size_t off = (size_t)(r0 + r) * 1024 + un;
            const float a  = acc[mi][0][r] + ba;
            const float ii = acc[mi][1][r] + bi;
            const float ff = acc[mi][2][r] + bfv;
            const float oo = acc[mi][3][r] + bo;
            const float c  = tanh_fast(a) * sigf(ii) + sigf(ff) * cprev[off];
            outh[off] = sigf(oo) * tanh_fast(c);
            outc[off] = c;
        }
    }
#undef STAGE_A
#undef STAGE_B
#undef LDA
#undef LDB
#undef RD_A
#undef RD_B
#undef SBAR
#undef VMFENCE
#undef MFMA16
#undef KITER
#undef ASB
#undef BSB
}

// ---------------- launch ----------------

extern "C" void kernel_launch(void* const* d_in, const int* in_sizes, int n_in,
                              void* d_out, int out_size, void* d_ws, size_t ws_size,
                              hipStream_t stream) {
    const float* top_buf = (const float*)d_in[0];
    const float* s1      = (const float*)d_in[1];
    const float* s2      = (const float*)d_in[2];
    const float* hprev   = (const float*)d_in[3];
    const float* cprev   = (const float*)d_in[4];
    const float* Wb      = (const float*)d_in[5];
    const float* W1      = (const float*)d_in[6];
    const float* W2      = (const float*)d_in[7];
    const float* Wl      = (const float*)d_in[8];
    const float* bl      = (const float*)d_in[9];

    unsigned short* Abf = (unsigned short*)d_ws;                 // 32 MB
    unsigned short* Bt  = Abf + (size_t)4096 * 4096;             // 32 MB

    convert_AB<<<32768, 256, 0, stream>>>(top_buf, s1, s2, hprev,
                                          Wb, W1, W2, Wl, Abf, Bt);

    dim3 grid(16, 16);
    gemm_lstm<<<grid, 512, 0, stream>>>(Abf, Bt, bl, cprev, (float*)d_out);
}

// Round 7
// 147.662 us; speedup vs baseline: 1.7593x; 1.0003x over previous
//
#include <hip/hip_runtime.h>

// ---------------- helpers ----------------

typedef __bf16 bf16x8 __attribute__((ext_vector_type(8)));
typedef float  f32x4  __attribute__((ext_vector_type(4)));

__device__ __forceinline__ unsigned short f2bf(float x) {
    unsigned int u = __builtin_bit_cast(unsigned int, x);
    u = (u + 0x7fffu + ((u >> 16) & 1u)) >> 16;
    return (unsigned short)u;
}

__device__ __forceinline__ void gl2lds16(const unsigned short* g, unsigned short* l) {
    __builtin_amdgcn_global_load_lds(
        (const __attribute__((address_space(1))) unsigned int*)g,
        (__attribute__((address_space(3))) unsigned int*)l,
        16, 0, 0);
}

__device__ __forceinline__ float sigf(float x) {
    return __builtin_amdgcn_rcpf(1.f + __expf(-x));
}
__device__ __forceinline__ float tanh_fast(float x) {
    return 2.f * __builtin_amdgcn_rcpf(1.f + __expf(-2.f * x)) - 1.f;
}

// ---------------- fused conversion kernel ----------------
// blocks [0,16384): activations -> bf16 A [4096][4096]
// blocks [16384,32768): weights -> bf16 B^T with gate-interleave permutation
//   Bt[p][k] = Wcat[k][ g*1024 + u ],  p = (u>>6)*256 + ((u>>4)&3)*64 + g*16 + (u&15)

__global__ void convert_AB(const float* __restrict__ A0, const float* __restrict__ A1,
                           const float* __restrict__ A2, const float* __restrict__ A3,
                           const float* __restrict__ Wb, const float* __restrict__ W1,
                           const float* __restrict__ W2, const float* __restrict__ Wl,
                           unsigned short* __restrict__ Abf,
                           unsigned short* __restrict__ Bt) {
    __shared__ float t[32][33];
    if (blockIdx.x < 16384) {
        int idx = blockIdx.x * 256 + threadIdx.x;
        int e0  = idx * 4;
        int b   = e0 >> 12;
        int k   = e0 & 4095;
        const float* S = (k < 1024) ? A0 : (k < 2048) ? A1 : (k < 3072) ? A2 : A3;
        int col = k & 1023;
        const float4 v = *reinterpret_cast<const float4*>(S + (size_t)b * 1024 + col);
        ushort4 o;
        o.x = f2bf(v.x); o.y = f2bf(v.y); o.z = f2bf(v.z); o.w = f2bf(v.w);
        *reinterpret_cast<ushort4*>(Abf + (size_t)b * 4096 + k) = o;
    } else {
        int tile = blockIdx.x - 16384;    // 128 j-tiles x 128 k-tiles
        int jt = tile & 127, kt = tile >> 7;
        int j0 = jt * 32, k0 = kt * 32;
        int ksel = k0 >> 10;
        const float* S = (ksel == 0) ? Wb : (ksel == 1) ? W1 : (ksel == 2) ? W2 : Wl;
        int kloc = k0 & 1023;
        int tx = threadIdx.x & 31, ty = threadIdx.x >> 5;
#pragma unroll
        for (int i = 0; i < 4; ++i) {
            int r = ty + i * 8;
            t[r][tx] = S[(size_t)(kloc + r) * 4096 + j0 + tx];
        }
        __syncthreads();
        int g = j0 >> 10;
        int nbase = j0 & 1023;
#pragma unroll
        for (int i = 0; i < 4; ++i) {
            int jj = ty + i * 8;
            int u  = nbase + jj;
            int p  = (u >> 6) * 256 + ((u >> 4) & 3) * 64 + g * 16 + (u & 15);
            Bt[(size_t)p * 4096 + k0 + tx] = f2bf(t[tx][jj]);
        }
    }
}

// ---------------- 256x256 GEMM, 2-barrier K-tile, pinned interleave ----------------
// Dataflow identical to round 6 (2 barriers/K-tile, counted vmcnt(4), verified).
// NEW: sched_barrier(0) seams pin the source-order alternation
//   [12 reads][MFMA q0] B2 [B-stages][4 reads][q1][4 reads][q2][4 reads][q3] vmcnt B1
// so the compiler cannot re-cluster all 24 ds_reads into one flood at the top
// of the K-tile (which serializes the LDS pipe against the matrix pipe).
// Each 4-read batch hides under the previous quad's MFMA drain.

__global__ __launch_bounds__(512, 2) void gemm_lstm(
        const unsigned short* __restrict__ A,
        const unsigned short* __restrict__ Bt,
        const float* __restrict__ bias,
        const float* __restrict__ cprev,
        float* __restrict__ out) {
    __shared__ unsigned short lds[65536];          // 128 KiB
#define ASB(b) (lds + (b) * 16384)
#define BSB(b) (lds + 32768 + (b) * 16384)

    const int tid  = threadIdx.x;
    const int wid  = tid >> 6;
    const int lane = tid & 63;
    const int wm = wid >> 2, wn = wid & 3;         // 2 x 4 wave grid
    const int lr = lane & 15, lq = lane >> 4;
    const int bm = blockIdx.y, bc = blockIdx.x;

    // staging geometry: half-tile = 128 rows x 64 cols = 16 KB; 2 chunks/thread
    const int X0 = wid * 1024 + lane * 16;                 // j=0 portion, rows 0..63
    const int rs = X0 >> 7;
    const int cs = ((X0 & 127) ^ ((rs & 7) << 4)) >> 1;    // element col (pre-swizzled src)
    const unsigned short* Agb = A  + ((size_t)(bm * 256 + rs)) * 4096 + cs;
    const unsigned short* Bgb = Bt + ((size_t)(bc * 256 + rs)) * 4096 + cs;

    // ds_read fragment col offsets (elements), read-side swizzle
    const int swz = (lr & 7) << 4;
    const int ca0 = ((lq * 16) ^ swz) >> 1;        // ks=0
    const int ca1 = ((64 + lq * 16) ^ swz) >> 1;   // ks=1

    f32x4 acc[8][4] = {};                          // acc[mi][gate]

#define STAGE_A(b, h, kt) do {                                               \
        unsigned short* _d = ASB(b) + (h) * 8192 + wid * 512;                \
        const unsigned short* _s = Agb + (size_t)((h) * 128) * 4096 + (kt) * 64; \
        gl2lds16(_s, _d);                                                    \
        gl2lds16(_s + 64 * 4096, _d + 4096);                                 \
    } while (0)
#define STAGE_B(b, h, kt) do {                                               \
        unsigned short* _d = BSB(b) + (h) * 8192 + wid * 512;                \
        const unsigned short* _s = Bgb + (size_t)((h) * 128) * 4096 + (kt) * 64; \
        gl2lds16(_s, _d);                                                    \
        gl2lds16(_s + 64 * 4096, _d + 4096);                                 \
    } while (0)
#define LDA(buf, mi, cax) (*reinterpret_cast<const bf16x8*>((buf) + (wm * 128 + (mi) * 16 + lr) * 64 + (cax)))
#define LDB(buf, ni, cax) (*reinterpret_cast<const bf16x8*>((buf) + (wn * 64  + (ni) * 16 + lr) * 64 + (cax)))
#define RD_A(DST, BUF, MI0) do {                                             \
        _Pragma("unroll")                                                    \
        for (int m = 0; m < 2; ++m) {                                        \
            DST[m][0] = LDA(BUF, (MI0) + m, ca0);                            \
            DST[m][1] = LDA(BUF, (MI0) + m, ca1);                            \
        } } while (0)
#define RD_B(DST, BUF) do {                                                  \
        _Pragma("unroll")                                                    \
        for (int n = 0; n < 4; ++n) {                                        \
            DST[n][0] = LDB(BUF, n, ca0);                                    \
            DST[n][1] = LDB(BUF, n, ca1);                                    \
        } } while (0)
#define SBAR() __builtin_amdgcn_s_barrier()
#define SFENCE() __builtin_amdgcn_sched_barrier(0)
#define VMFENCE() asm volatile("s_waitcnt vmcnt(4)" ::: "memory")
#define MFMA16(P, AF, BF)                                                    \
        __builtin_amdgcn_s_setprio(1);                                       \
        _Pragma("unroll")                                                    \
        for (int m = 0; m < 2; ++m)                                          \
        _Pragma("unroll")                                                    \
        for (int ks = 0; ks < 2; ++ks)                                       \
        _Pragma("unroll")                                                    \
        for (int ni = 0; ni < 4; ++ni)                                       \
            acc[(P)*2 + m][ni] = __builtin_amdgcn_mfma_f32_16x16x32_bf16(    \
                AF[m][ks], BF[ni][ks], acc[(P)*2 + m][ni], 0, 0, 0);         \
        __builtin_amdgcn_s_setprio(0)

#define KITER(T, PAR) do {                                                   \
        const unsigned short* Ac = ASB(PAR);                                 \
        const unsigned short* Bc = BSB(PAR);                                 \
        const int ktA = ((T) < 63) ? (T) + 1 : 63;                           \
        const int ktB = ((T) < 62) ? (T) + 2 : 63;                           \
        STAGE_A(PAR ^ 1, 0, ktA);                                            \
        STAGE_A(PAR ^ 1, 1, ktA);                                            \
        bf16x8 bfr[4][2];                                                    \
        bf16x8 af[2][2];                                                     \
        RD_B(bfr, Bc);                                                       \
        RD_A(af, Ac, 0);                                                     \
        SFENCE();                                                            \
        MFMA16(0, af, bfr);                                                  \
        SFENCE();                                                            \
        SBAR();   /* B2: all waves' B-frags in regs -> B region writable */  \
        STAGE_B(PAR, 0, ktB);                                                \
        STAGE_B(PAR, 1, ktB);                                                \
        RD_A(af, Ac, 2);                                                     \
        SFENCE();                                                            \
        MFMA16(1, af, bfr);                                                  \
        SFENCE();                                                            \
        RD_A(af, Ac, 4);                                                     \
        SFENCE();                                                            \
        MFMA16(2, af, bfr);                                                  \
        SFENCE();                                                            \
        RD_A(af, Ac, 6);                                                     \
        SFENCE();                                                            \
        MFMA16(3, af, bfr);                                                  \
        VMFENCE();                                                           \
        SBAR();   /* B1: tile T+1 staged data ready */                       \
    } while (0)

    // ---- prologue: tile0 A+B, tile1 B staged ----
    STAGE_A(0, 0, 0); STAGE_A(0, 1, 0);
    STAGE_B(0, 0, 0); STAGE_B(0, 1, 0);
    STAGE_B(1, 0, 1); STAGE_B(1, 1, 1);
    VMFENCE();                                     // tile0's 8 loads landed
    SBAR();

    for (int u = 0; u < 32; ++u) {
        KITER(2 * u, 0);
        KITER(2 * u + 1, 1);
    }

    // ---- fused LSTM epilogue: lane lr holds a,i,f,o of unit u in ni=0..3 ----
    const int un = bc * 64 + wn * 16 + lr;
    const float ba  = bias[un];
    const float bi  = bias[1024 + un];
    const float bfv = bias[2048 + un];
    const float bo  = bias[3072 + un];
    float* outh = out;
    float* outc = out + (size_t)4096 * 1024;

#pragma unroll
    for (int mi = 0; mi < 8; ++mi) {
        const int r0 = bm * 256 + wm * 128 + mi * 16 + lq * 4;
#pragma unroll
        for (int r = 0; r < 4; ++r) {
            const size_t off = (size_t)(r0 + r) * 1024 + un;
            const float a  = acc[mi][0][r] + ba;
            const float ii = acc[mi][1][r] + bi;
            const float ff = acc[mi][2][r] + bfv;
            const float oo = acc[mi][3][r] + bo;
            const float c  = tanh_fast(a) * sigf(ii) + sigf(ff) * cprev[off];
            outh[off] = sigf(oo) * tanh_fast(c);
            outc[off] = c;
        }
    }
#undef STAGE_A
#undef STAGE_B
#undef LDA
#undef LDB
#undef RD_A
#undef RD_B
#undef SBAR
#undef SFENCE
#undef VMFENCE
#undef MFMA16
#undef KITER
#undef ASB
#undef BSB
}

// ---------------- launch ----------------

extern "C" void kernel_launch(void* const* d_in, const int* in_sizes, int n_in,
                              void* d_out, int out_size, void* d_ws, size_t ws_size,
                              hipStream_t stream) {
    const float* top_buf = (const float*)d_in[0];
    const float* s1      = (const float*)d_in[1];
    const float* s2      = (const float*)d_in[2];
    const float* hprev   = (const float*)d_in[3];
    const float* cprev   = (const float*)d_in[4];
    const float* Wb      = (const float*)d_in[5];
    const float* W1      = (const float*)d_in[6];
    const float* W2      = (const float*)d_in[7];
    const float* Wl      = (const float*)d_in[8];
    const float* bl      = (const float*)d_in[9];

    unsigned short* Abf = (unsigned short*)d_ws;                 // 32 MB
    unsigned short* Bt  = Abf + (size_t)4096 * 4096;             // 32 MB

    convert_AB<<<32768, 256, 0, stream>>>(top_buf, s1, s2, hprev,
                                          Wb, W1, W2, Wl, Abf, Bt);

    dim3 grid(16, 16);
    gemm_lstm<<<grid, 512, 0, stream>>>(Abf, Bt, bl, cprev, (float*)d_out);
}